// Round 5
// baseline (424.222 us; speedup 1.0000x reference)
//
#include <hip/hip_runtime.h>
#include <stdint.h>

using bf16x8 = __attribute__((ext_vector_type(8))) short;
using f32x4  = __attribute__((ext_vector_type(4))) float;
using f32x16 = __attribute__((ext_vector_type(16))) float;
using u16x4  = __attribute__((ext_vector_type(4))) unsigned short;
using u16x8  = __attribute__((ext_vector_type(8))) unsigned short;

__device__ __forceinline__ unsigned short f2bf(float f) {
  unsigned u = __builtin_bit_cast(unsigned, f);
  u = (u + 0x7FFFu + ((u >> 16) & 1u)) >> 16;   // RTNE
  return (unsigned short)u;
}
__device__ __forceinline__ float bf2f(unsigned short h) {
  unsigned u = ((unsigned)h) << 16;
  return __builtin_bit_cast(float, u);
}

// ---------------- f32 -> bf16 cast, vectorized (G13) ----------------
__global__ __launch_bounds__(256) void cvt_f32_to_bf16(
    const float* __restrict__ in, unsigned short* __restrict__ out, long n8) {
  long i = (long)blockIdx.x * blockDim.x + threadIdx.x;
  const long stride = (long)gridDim.x * blockDim.x;
  for (; i < n8; i += stride) {
    float4 a = ((const float4*)in)[2 * i];
    float4 b = ((const float4*)in)[2 * i + 1];
    u16x8 o = { f2bf(a.x), f2bf(a.y), f2bf(a.z), f2bf(a.w),
                f2bf(b.x), f2bf(b.y), f2bf(b.z), f2bf(b.w) };
    ((u16x8*)out)[i] = o;
  }
}

// ---------------- fused cast+transpose: out[c][r] = bf16(in[r][c]) ----------------
__global__ __launch_bounds__(256) void transpose_cast(
    const float* __restrict__ in, unsigned short* __restrict__ out, int R, int C) {
  __shared__ unsigned short tile[64][68];
  const int c0 = blockIdx.x * 64, r0 = blockIdx.y * 64;
  const int t = threadIdx.x;
#pragma unroll
  for (int i = 0; i < 4; ++i) {
    int ch = t + i * 256;
    int r = ch >> 4, c4 = (ch & 15) * 4;
    float4 v = *(const float4*)&in[(size_t)(r0 + r) * C + c0 + c4];
    u16x4 o = { f2bf(v.x), f2bf(v.y), f2bf(v.z), f2bf(v.w) };
    *(u16x4*)&tile[r][c4] = o;
  }
  __syncthreads();
#pragma unroll
  for (int i = 0; i < 4; ++i) {
    int ch = t + i * 256;
    int r = ch >> 4, c4 = (ch & 15) * 4;
    u16x4 v;
#pragma unroll
    for (int j = 0; j < 4; ++j) v[j] = tile[c4 + j][r];
    *(u16x4*)&out[(size_t)(c0 + r) * R + r0 + c4] = v;
  }
}

// ---------------- f32 matvec: out = W @ x + b  (combined biases) ----------------
__global__ __launch_bounds__(256) void bias_matvec(
    const float* __restrict__ W, const float* __restrict__ x,
    const float* __restrict__ b, float* __restrict__ out, int n) {
  const int row = blockIdx.x;
  const float* wr = W + (long)row * n;
  float s = 0.f;
  for (int j = threadIdx.x; j < n; j += 256) s += wr[j] * x[j];
#pragma unroll
  for (int o = 32; o; o >>= 1) s += __shfl_xor(s, o);
  __shared__ float red[4];
  if ((threadIdx.x & 63) == 0) red[threadIdx.x >> 6] = s;
  __syncthreads();
  if (threadIdx.x == 0) out[row] = red[0] + red[1] + red[2] + red[3] + b[row];
}

// ---------------- merge row-sum partials -> reciprocal ----------------
__global__ __launch_bounds__(256) void merge_invl(
    const float* __restrict__ Lpart, float* __restrict__ invL, long nrows) {
  long r = (long)blockIdx.x * 256 + threadIdx.x;
  if (r < nrows) {
    const float* p = Lpart + r * 8;
    float s = 0.f;
#pragma unroll
    for (int i = 0; i < 8; ++i) s += p[i];
    invL[r] = 1.f / s;
  }
}

// ---------------- 128x128 m97-structure GEMM (small weight combos only) ----------
template <int EPI>  // 0: +bias[col]->bf16 ; 1: *scale->bf16
__global__ __launch_bounds__(256, 4) void gemm_bt(
    const unsigned short* __restrict__ A, const unsigned short* __restrict__ B,
    void* __restrict__ C, const float* __restrict__ bias,
    int M, int N, int K, float scale) {
  __shared__ unsigned short lA[2][128][32];
  __shared__ unsigned short lB[2][128][32];
  const int t = threadIdx.x;
  const int gx = gridDim.x, gy = gridDim.y;
  int bid = blockIdx.x + gx * blockIdx.y;
  const int nwg = gx * gy;
  const int chunk = nwg >> 3;
  int lid = (bid & 7) * chunk + (bid >> 3);
  const int bn = lid % gx;
  const int bm = lid / gx;

  const unsigned short* Ab = A + (long)bm * 128 * K;
  const unsigned short* Bb = B + (long)bn * 128 * K;

  const int lane = t & 63;
  const int wv = t >> 6, wm = wv >> 1, wn = wv & 1;
  const int fr = lane & 15, kg = lane >> 4;
  const int srow  = t >> 2;
  const int scol  = (t & 3) * 8;
  const int wbyte = (t >> 6) * 1024;

  f32x4 acc[4][4] = {};
  const int NT = K >> 5;

  auto stage = [&](int buf, int kt) {
    const unsigned short* sa = Ab + kt * 32;
    const unsigned short* sb = Bb + kt * 32;
#pragma unroll
    for (int p = 0; p < 2; ++p) {
      const unsigned short* srcA = sa + (long)(p * 64 + srow) * K + scol;
      const unsigned short* srcB = sb + (long)(p * 64 + srow) * K + scol;
      char* dA = (char*)(&lA[buf][0][0]) + p * 4096 + wbyte;
      char* dB = (char*)(&lB[buf][0][0]) + p * 4096 + wbyte;
      __builtin_amdgcn_global_load_lds(
          (const __attribute__((address_space(1))) void*)srcA,
          (__attribute__((address_space(3))) void*)dA, 16, 0, 0);
      __builtin_amdgcn_global_load_lds(
          (const __attribute__((address_space(1))) void*)srcB,
          (__attribute__((address_space(3))) void*)dB, 16, 0, 0);
    }
  };

  stage(0, 0);
  for (int kt = 0; kt < NT; ++kt) {
    const int cur = kt & 1;
    __syncthreads();
    if (kt + 1 < NT) stage(cur ^ 1, kt + 1);
    bf16x8 av[4], bv[4];
#pragma unroll
    for (int m = 0; m < 4; ++m)
      av[m] = *(const bf16x8*)&lA[cur][wm * 64 + m * 16 + fr][kg * 8];
#pragma unroll
    for (int n = 0; n < 4; ++n)
      bv[n] = *(const bf16x8*)&lB[cur][wn * 64 + n * 16 + fr][kg * 8];
#pragma unroll
    for (int m = 0; m < 4; ++m)
#pragma unroll
      for (int n = 0; n < 4; ++n)
        acc[m][n] = __builtin_amdgcn_mfma_f32_16x16x32_bf16(av[m], bv[n], acc[m][n], 0, 0, 0);
  }

  const int row0 = bm * 128 + wm * 64 + kg * 4;
  const int col0 = bn * 128 + wn * 64 + fr;
#pragma unroll
  for (int m = 0; m < 4; ++m)
#pragma unroll
    for (int n = 0; n < 4; ++n) {
      const int col = col0 + n * 16;
#pragma unroll
      for (int r = 0; r < 4; ++r) {
        const int row = row0 + m * 16 + r;
        float v = acc[m][n][r];
        if constexpr (EPI == 1) v *= scale; else v += bias[col];
        ((unsigned short*)C)[(long)row * N + col] = f2bf(v);
      }
    }
}

// ---------------- 256x256 GEMM, 32x32x16 MFMA, 1 barrier/K-tile ----------------
// 512 thr (8 waves 2Mx4N, wave tile 128x64 = 4x2 of 32x32), BK=64, 128 KiB LDS
// double-buffered. Staging (global_load_lds w16) issued at TILE START into buf^1;
// its ~900cy HBM latency hides under ~2000cy of this tile's compute, so the
// pre-barrier vmcnt(0) is stale/free (fixes m97's drain-stall). Compiler
// interleaves the 24 ds_reads with 32 MFMAs via its own counted lgkmcnt.
// Safety: each wave drains own ds_reads (lgkmcnt 0) + own staging (vmcnt 0)
// before signaling the single per-tile barrier -> buffer reuse is race-free.
// LDS layout: 1024B subtiles [row16][col32e]; within: r15*64 + (colb ^ ((r15>>3)<<5)
// ^ (risub&1 ? 16 : 0)). Staging source pre-permuted to match (rule #21).
// EPI: 0 +bias[col]->bf16 | 1 *scale->bf16 | 3 +bias[col]->f32 | 4 +bias[row]->bf16
//      5 exp2(acc*scale)->bf16 + row-partial sums to aux | 6 acc*bias[row]+resid->bf16
template <int EPI>
__global__ __launch_bounds__(512, 2) void gemm256(
    const unsigned short* __restrict__ A, const unsigned short* __restrict__ B,
    void* __restrict__ C, const float* __restrict__ bias,
    const unsigned short* __restrict__ resid, float* __restrict__ aux,
    int N, int K, long sA, long sB, long sC, long sR, float scale) {
  __shared__ char lds[131072];
  const int t = threadIdx.x;
  const int lane = t & 63, wid = t >> 6;

  const int gx = gridDim.x, gy = gridDim.y;
  int bid = blockIdx.x + gx * (blockIdx.y + gy * blockIdx.z);
  const int nwg = gx * gy * (int)gridDim.z;
  const int chunk = nwg >> 3;
  int lid = (bid & 7) * chunk + (bid >> 3);
  const int bn = lid % gx; lid /= gx;
  const int bm = lid % gy;
  const int bz = lid / gy;

  const unsigned short* Ab = A + (long)bz * sA + (long)bm * 256 * K;
  const unsigned short* Bb = B + (long)bz * sB + (long)bn * 256 * K;

  // ---- staging (linear LDS dest, inverse-swizzled global source) ----
  // subtile (h,s,wid): rows h*128+(wid>>1)*16+s*64.., cols (wid&1)*32..; ri parity = (wid>>1)&1
  const int colswz = (((lane & 3) * 8) ^ ((lane >> 5) * 16) ^ (((wid >> 1) & 1) << 3));
  const int r0s = (wid >> 1) * 16 + (lane >> 2);
  const int scol = (wid & 1) * 32 + colswz;

  auto issue = [&](const unsigned short* base, int kt, int h, int bufbyte) {
#pragma unroll
    for (int s = 0; s < 2; ++s) {
      const unsigned short* src = base + (long)(h * 128 + r0s + s * 64) * K + kt * 64 + scol;
      char* dst = lds + bufbyte + h * 16384 + s * 8192 + wid * 1024;
      __builtin_amdgcn_global_load_lds(
          (const __attribute__((address_space(1))) void*)src,
          (__attribute__((address_space(3))) void*)dst, 16, 0, 0);
    }
  };
  auto issueTile = [&](int kt, int buf) {
    issue(Ab, kt, 0, buf * 32768);
    issue(Ab, kt, 1, buf * 32768);
    issue(Bb, kt, 0, 65536 + buf * 32768);
    issue(Bb, kt, 1, 65536 + buf * 32768);
  };

  // ---- fragment addressing (32x32x16) ----
  const int wm = wid >> 2, wn = wid & 3;      // 2M x 4N waves
  const int rl = lane & 31;
  const int r15 = rl & 15, rsub = rl >> 4;
  const int hi16b = (lane >> 5) * 16;         // byte offset of K-half
  const int swzmask = ((r15 >> 3) << 5) ^ (rsub << 4);
  const int laneBase = rsub * 2048 + r15 * 64;
  int cp[4];
#pragma unroll
  for (int ks = 0; ks < 4; ++ks) {
    const int cb = ks * 32 + hi16b;
    cp[ks] = ((cb & 63) ^ swzmask) + ((cb >> 6) << 10);
  }

  f32x16 acc[4][2] = {};
  const int NT = K >> 6;

  issueTile(0, 0);
  asm volatile("s_waitcnt vmcnt(0)" ::: "memory");
  __builtin_amdgcn_s_barrier();
  asm volatile("" ::: "memory");

  int cur = 0;
  for (int kt = 0; kt < NT; ++kt) {
    if (kt + 1 < NT) issueTile(kt + 1, cur ^ 1);   // latency spans whole tile
    const char* ab = lds + cur * 32768;
    const char* bb = lds + 65536 + cur * 32768;
#pragma unroll
    for (int ks = 0; ks < 4; ++ks) {
      bf16x8 bf0 = *(const bf16x8*)(bb + (wn * 4 + 0) * 2048 + laneBase + cp[ks]);
      bf16x8 bf1 = *(const bf16x8*)(bb + (wn * 4 + 2) * 2048 + laneBase + cp[ks]);
      bf16x8 af[4];
#pragma unroll
      for (int mt = 0; mt < 4; ++mt)
        af[mt] = *(const bf16x8*)(ab + (wm * 8 + mt * 2) * 2048 + laneBase + cp[ks]);
#pragma unroll
      for (int mt = 0; mt < 4; ++mt) {
        acc[mt][0] = __builtin_amdgcn_mfma_f32_32x32x16_bf16(af[mt], bf0, acc[mt][0], 0, 0, 0);
        acc[mt][1] = __builtin_amdgcn_mfma_f32_32x32x16_bf16(af[mt], bf1, acc[mt][1], 0, 0, 0);
      }
    }
    // drain own reads (buf reuse safety) + own staging (landed long ago)
    asm volatile("s_waitcnt vmcnt(0) lgkmcnt(0)" ::: "memory");
    __builtin_amdgcn_s_barrier();
    asm volatile("" ::: "memory");
    cur ^= 1;
  }

  // C/D layout 32x32: col = lane&31, row = (reg&3) + 8*(reg>>2) + 4*(lane>>5)  [m74/m101]
  const int cl = lane & 31;
  const int rhalf = (lane >> 5) * 4;
  const int row0g = bm * 256 + wm * 128;
  const int col0g = bn * 256 + wn * 64;
  const long cb2 = (long)bz * sC;

  if constexpr (EPI == 5) {
    // e = exp2(acc*scale) (no max-sub; |scores| << 1), store bf16, row-sums -> aux
    float* lf = (float*)lds;   // 4 KiB scratch; all loop ds_reads drained
#pragma unroll
    for (int mt = 0; mt < 4; ++mt) {
#pragma unroll
      for (int reg = 0; reg < 16; ++reg) {
        const int rit = (reg & 3) + ((reg >> 2) << 3) + rhalf;
        const int row = row0g + mt * 32 + rit;
        float sv = 0.f;
#pragma unroll
        for (int nt = 0; nt < 2; ++nt) {
          float e = exp2f(acc[mt][nt][reg] * scale);
          unsigned short eb = f2bf(e);
          ((unsigned short*)C)[cb2 + (long)row * N + col0g + nt * 32 + cl] = eb;
          sv += bf2f(eb);
        }
#pragma unroll
        for (int o = 1; o < 32; o <<= 1) sv += __shfl_xor(sv, o);
        if (cl == 0) lf[wn * 256 + wm * 128 + mt * 32 + rit] = sv;
      }
    }
    __syncthreads();
    if (t < 256) {
      float s4 = lf[t] + lf[256 + t] + lf[512 + t] + lf[768 + t];
      aux[((long)bz * 2048 + bm * 256 + t) * 8 + bn] = s4;
    }
    return;
  }

#pragma unroll
  for (int mt = 0; mt < 4; ++mt)
#pragma unroll
    for (int nt = 0; nt < 2; ++nt) {
      const int col = col0g + nt * 32 + cl;
#pragma unroll
      for (int reg = 0; reg < 16; ++reg) {
        const int row = row0g + mt * 32 + (reg & 3) + ((reg >> 2) << 3) + rhalf;
        float v = acc[mt][nt][reg];
        if constexpr (EPI == 0) {
          v += bias[col];
          ((unsigned short*)C)[cb2 + (long)row * N + col] = f2bf(v);
        } else if constexpr (EPI == 1) {
          v *= scale;
          ((unsigned short*)C)[cb2 + (long)row * N + col] = f2bf(v);
        } else if constexpr (EPI == 3) {
          v += bias[col];
          ((float*)C)[cb2 + (long)row * N + col] = v;
        } else if constexpr (EPI == 4) {
          v += bias[row];
          ((unsigned short*)C)[cb2 + (long)row * N + col] = f2bf(v);
        } else {  // EPI == 6: PV normalize by invL[row] + residual q
          v = v * bias[(long)bz * 2048 + row] + bf2f(resid[(long)bz * sR + (long)row * N + col]);
          ((unsigned short*)C)[cb2 + (long)row * N + col] = f2bf(v);
        }
      }
    }
}

// ---------------- orchestration ----------------
extern "C" void kernel_launch(void* const* d_in, const int* in_sizes, int n_in,
                              void* d_out, int out_size, void* d_ws, size_t ws_size,
                              hipStream_t stream) {
  (void)in_sizes; (void)n_in; (void)out_size; (void)ws_size;
  const float* hist = (const float*)d_in[0];
  const float* comb = (const float*)d_in[1];
  const float* hW = (const float*)d_in[2];  const float* hb = (const float*)d_in[3];
  const float* cW = (const float*)d_in[4];  const float* cb = (const float*)d_in[5];
  const float* qW = (const float*)d_in[6];  const float* qb = (const float*)d_in[7];
  const float* kW = (const float*)d_in[8];
  const float* vW = (const float*)d_in[10]; const float* vb = (const float*)d_in[11];
  const float* oW = (const float*)d_in[12]; const float* ob = (const float*)d_in[13];

  constexpr int  Bn = 8, L = 2048, F = 1024;
  constexpr long NE = (long)Bn * L * F;
  constexpr long WE = (long)F * F;

  char* ws = (char*)d_ws;
  size_t off = 0;
  unsigned short* oWb = (unsigned short*)(ws + off); off += WE * 2;
  unsigned short* Wq  = (unsigned short*)(ws + off); off += WE * 2;
  unsigned short* Wkv = (unsigned short*)(ws + off); off += 2 * WE * 2;
  unsigned short* Wk  = Wkv;
  unsigned short* Wv  = Wkv + WE;
  float* bq = (float*)(ws + off); off += F * 4;
  float* bv = (float*)(ws + off); off += F * 4;
  float* Lpart = (float*)(ws + off); off += (size_t)Bn * L * 8 * 4;
  float* invL  = (float*)(ws + off); off += (size_t)Bn * L * 4;
  unsigned short* A0 = (unsigned short*)(ws + off); off += NE * 2;
  unsigned short* A1 = (unsigned short*)(ws + off); off += NE * 2;
  unsigned short* A2 = (unsigned short*)(ws + off); off += NE * 2;
  unsigned short* A3 = (unsigned short*)(ws + off); off += NE * 2;
  unsigned short* S  = (unsigned short*)(ws + off); off += (size_t)Bn * L * L * 2;
  unsigned short* hWt = S;
  unsigned short* cWt = S + WE;
  unsigned short* qWb = S + 2 * WE;
  unsigned short* kvWb = S + 3 * WE;

  transpose_cast<<<dim3(16, 16, 1), 256, 0, stream>>>(hW, hWt, F, F);
  transpose_cast<<<dim3(16, 16, 1), 256, 0, stream>>>(cW, cWt, F, F);
  cvt_f32_to_bf16<<<512, 256, 0, stream>>>(qW, qWb, WE / 8);
  cvt_f32_to_bf16<<<512, 256, 0, stream>>>(kW, kvWb, WE / 8);
  cvt_f32_to_bf16<<<512, 256, 0, stream>>>(vW, kvWb + WE, WE / 8);
  cvt_f32_to_bf16<<<512, 256, 0, stream>>>(oW, oWb, WE / 8);
  cvt_f32_to_bf16<<<2048, 256, 0, stream>>>(hist, A0, NE / 8);
  cvt_f32_to_bf16<<<2048, 256, 0, stream>>>(comb, A1, NE / 8);

  // combined biases: bq = qW·hb + qb ; bv = vW·cb + vb   (bk cancels in softmax)
  bias_matvec<<<F, 256, 0, stream>>>(qW, hb, qb, bq, F);
  bias_matvec<<<F, 256, 0, stream>>>(vW, cb, vb, bv, F);

  // combined weights: Wq = qW·hW ; [Wk;Wv] = [kW;vW]·cW
  gemm_bt<1><<<dim3(8, 8, 1), 256, 0, stream>>>(qWb, hWt, Wq, nullptr,
      1024, 1024, 1024, 1.0f);
  gemm_bt<1><<<dim3(8, 16, 1), 256, 0, stream>>>(kvWb, cWt, Wkv, nullptr,
      2048, 1024, 1024, 1.0f);

  const float S2 = 0.03125f * 1.44269504089f;  // (1/sqrt(F)) * log2(e), for exp2

  // q = hist·Wq^T + bq          -> A2
  gemm256<0><<<dim3(4, 64, 1), 512, 0, stream>>>(A0, Wq, A2, bq, nullptr, nullptr,
      1024, 1024, 0, 0, 0, 0, 0.f);
  // k = comb·Wk^T (no bias)     -> A0
  gemm256<1><<<dim3(4, 64, 1), 512, 0, stream>>>(A1, Wk, A0, nullptr, nullptr, nullptr,
      1024, 1024, 0, 0, 0, 0, 1.0f);
  // vt[b][f][l] = Wv·comb_b^T + bv[row]  -> A3
  gemm256<4><<<dim3(8, 4, Bn), 512, 0, stream>>>(Wv, A1, A3, bv, nullptr, nullptr,
      2048, 1024, 0, (long)L * F, (long)F * L, 0, 0.f);
  // E = exp2(q·k^T · S2)        -> S, row-sum partials -> Lpart
  gemm256<5><<<dim3(8, 8, Bn), 512, 0, stream>>>(A2, A0, S, nullptr, nullptr, Lpart,
      2048, 1024, (long)L * F, (long)L * F, (long)L * L, 0, S2);
  // invL = 1/rowsum
  merge_invl<<<64, 256, 0, stream>>>(Lpart, invL, (long)Bn * L);
  // ao = (E·vt^T)·invL + q      -> A1
  gemm256<6><<<dim3(4, 8, Bn), 512, 0, stream>>>(S, A3, A1, invL, A2, nullptr,
      1024, 2048, (long)L * L, (long)F * L, (long)L * F, (long)L * F, 0.f);
  // out = ao·oW^T + ob          -> d_out (f32)
  gemm256<3><<<dim3(4, 64, 1), 512, 0, stream>>>(A1, oWb, (float*)d_out, ob, nullptr, nullptr,
      1024, 1024, 0, 0, 0, 0, 0.f);
}

// Round 7
// 400.430 us; speedup vs baseline: 1.0594x; 1.0594x over previous
//
#include <hip/hip_runtime.h>
#include <stdint.h>

using bf16x8 = __attribute__((ext_vector_type(8))) short;
using f32x4  = __attribute__((ext_vector_type(4))) float;
using u16x4  = __attribute__((ext_vector_type(4))) unsigned short;
using u16x8  = __attribute__((ext_vector_type(8))) unsigned short;

__device__ __forceinline__ unsigned short f2bf(float f) {
  unsigned u = __builtin_bit_cast(unsigned, f);
  u = (u + 0x7FFFu + ((u >> 16) & 1u)) >> 16;   // RTNE
  return (unsigned short)u;
}
__device__ __forceinline__ float bf2f(unsigned short h) {
  unsigned u = ((unsigned)h) << 16;
  return __builtin_bit_cast(float, u);
}

// ---------------- f32 -> bf16 cast, vectorized (G13) ----------------
__global__ __launch_bounds__(256) void cvt_f32_to_bf16(
    const float* __restrict__ in, unsigned short* __restrict__ out, long n8) {
  long i = (long)blockIdx.x * blockDim.x + threadIdx.x;
  const long stride = (long)gridDim.x * blockDim.x;
  for (; i < n8; i += stride) {
    float4 a = ((const float4*)in)[2 * i];
    float4 b = ((const float4*)in)[2 * i + 1];
    u16x8 o = { f2bf(a.x), f2bf(a.y), f2bf(a.z), f2bf(a.w),
                f2bf(b.x), f2bf(b.y), f2bf(b.z), f2bf(b.w) };
    ((u16x8*)out)[i] = o;
  }
}

// ---------------- fused cast+transpose: out[c][r] = bf16(in[r][c]) ----------------
__global__ __launch_bounds__(256) void transpose_cast(
    const float* __restrict__ in, unsigned short* __restrict__ out, int R, int C) {
  __shared__ unsigned short tile[64][68];
  const int c0 = blockIdx.x * 64, r0 = blockIdx.y * 64;
  const int t = threadIdx.x;
#pragma unroll
  for (int i = 0; i < 4; ++i) {
    int ch = t + i * 256;
    int r = ch >> 4, c4 = (ch & 15) * 4;
    float4 v = *(const float4*)&in[(size_t)(r0 + r) * C + c0 + c4];
    u16x4 o = { f2bf(v.x), f2bf(v.y), f2bf(v.z), f2bf(v.w) };
    *(u16x4*)&tile[r][c4] = o;
  }
  __syncthreads();
#pragma unroll
  for (int i = 0; i < 4; ++i) {
    int ch = t + i * 256;
    int r = ch >> 4, c4 = (ch & 15) * 4;
    u16x4 v;
#pragma unroll
    for (int j = 0; j < 4; ++j) v[j] = tile[c4 + j][r];
    *(u16x4*)&out[(size_t)(c0 + r) * R + r0 + c4] = v;
  }
}

// ---------------- f32 matvec: out = W @ x + b  (combined biases) ----------------
__global__ __launch_bounds__(256) void bias_matvec(
    const float* __restrict__ W, const float* __restrict__ x,
    const float* __restrict__ b, float* __restrict__ out, int n) {
  const int row = blockIdx.x;
  const float* wr = W + (long)row * n;
  float s = 0.f;
  for (int j = threadIdx.x; j < n; j += 256) s += wr[j] * x[j];
#pragma unroll
  for (int o = 32; o; o >>= 1) s += __shfl_xor(s, o);
  __shared__ float red[4];
  if ((threadIdx.x & 63) == 0) red[threadIdx.x >> 6] = s;
  __syncthreads();
  if (threadIdx.x == 0) out[row] = red[0] + red[1] + red[2] + red[3] + b[row];
}

// ---------------- merge row-sum partials -> reciprocal ----------------
__global__ __launch_bounds__(256) void merge_invl(
    const float* __restrict__ Lpart, float* __restrict__ invL, long nrows) {
  long r = (long)blockIdx.x * 256 + threadIdx.x;
  if (r < nrows) {
    const float* p = Lpart + r * 8;
    float s = 0.f;
#pragma unroll
    for (int i = 0; i < 8; ++i) s += p[i];
    invL[r] = 1.f / s;
  }
}

// ---------------- 128x128 m97-structure GEMM (small weight combos only) ----------
template <int EPI>  // 0: +bias[col]->bf16 ; 1: *scale->bf16
__global__ __launch_bounds__(256, 4) void gemm_bt(
    const unsigned short* __restrict__ A, const unsigned short* __restrict__ B,
    void* __restrict__ C, const float* __restrict__ bias,
    int M, int N, int K, float scale) {
  __shared__ unsigned short lA[2][128][32];
  __shared__ unsigned short lB[2][128][32];
  const int t = threadIdx.x;
  const int gx = gridDim.x, gy = gridDim.y;
  int bid = blockIdx.x + gx * blockIdx.y;
  const int nwg = gx * gy;
  const int chunk = nwg >> 3;
  int lid = (bid & 7) * chunk + (bid >> 3);
  const int bn = lid % gx;
  const int bm = lid / gx;

  const unsigned short* Ab = A + (long)bm * 128 * K;
  const unsigned short* Bb = B + (long)bn * 128 * K;

  const int lane = t & 63;
  const int wv = t >> 6, wm = wv >> 1, wn = wv & 1;
  const int fr = lane & 15, kg = lane >> 4;
  const int srow  = t >> 2;
  const int scol  = (t & 3) * 8;
  const int wbyte = (t >> 6) * 1024;

  f32x4 acc[4][4] = {};
  const int NT = K >> 5;

  auto stage = [&](int buf, int kt) {
    const unsigned short* sa = Ab + kt * 32;
    const unsigned short* sb = Bb + kt * 32;
#pragma unroll
    for (int p = 0; p < 2; ++p) {
      const unsigned short* srcA = sa + (long)(p * 64 + srow) * K + scol;
      const unsigned short* srcB = sb + (long)(p * 64 + srow) * K + scol;
      char* dA = (char*)(&lA[buf][0][0]) + p * 4096 + wbyte;
      char* dB = (char*)(&lB[buf][0][0]) + p * 4096 + wbyte;
      __builtin_amdgcn_global_load_lds(
          (const __attribute__((address_space(1))) void*)srcA,
          (__attribute__((address_space(3))) void*)dA, 16, 0, 0);
      __builtin_amdgcn_global_load_lds(
          (const __attribute__((address_space(1))) void*)srcB,
          (__attribute__((address_space(3))) void*)dB, 16, 0, 0);
    }
  };

  stage(0, 0);
  for (int kt = 0; kt < NT; ++kt) {
    const int cur = kt & 1;
    __syncthreads();
    if (kt + 1 < NT) stage(cur ^ 1, kt + 1);
    bf16x8 av[4], bv[4];
#pragma unroll
    for (int m = 0; m < 4; ++m)
      av[m] = *(const bf16x8*)&lA[cur][wm * 64 + m * 16 + fr][kg * 8];
#pragma unroll
    for (int n = 0; n < 4; ++n)
      bv[n] = *(const bf16x8*)&lB[cur][wn * 64 + n * 16 + fr][kg * 8];
#pragma unroll
    for (int m = 0; m < 4; ++m)
#pragma unroll
      for (int n = 0; n < 4; ++n)
        acc[m][n] = __builtin_amdgcn_mfma_f32_16x16x32_bf16(av[m], bv[n], acc[m][n], 0, 0, 0);
  }

  const int row0 = bm * 128 + wm * 64 + kg * 4;
  const int col0 = bn * 128 + wn * 64 + fr;
#pragma unroll
  for (int m = 0; m < 4; ++m)
#pragma unroll
    for (int n = 0; n < 4; ++n) {
      const int col = col0 + n * 16;
#pragma unroll
      for (int r = 0; r < 4; ++r) {
        const int row = row0 + m * 16 + r;
        float v = acc[m][n][r];
        if constexpr (EPI == 1) v *= scale; else v += bias[col];
        ((unsigned short*)C)[(long)row * N + col] = f2bf(v);
      }
    }
}

// ---------------- 256x256 8-phase 2-barrier GEMM (m201 schedule, addr-diet) --------
// 512 thr (8 waves 2Mx4N), 16x16x32 MFMA, BK=64, 128 KiB LDS dbuf, st_16x32 XOR
// swizzle (T2, bank-conflict 0 verified), counted vmcnt(4) once per half-iter (T4),
// setprio around MFMA (T5), XCD-chunked bijective grid swizzle (T1).
// Phase = { ds_reads ; stage-issues ; [mp3: vmcnt] ; barrier ; lgkmcnt(0)+SGB ;
//           setprio(1) ; 16 MFMA ; setprio(0) ; barrier }   (m201 form)
// Addr diet: staging uses two per-wave running pointers (aPtr/bPtr advance +128
// elems per iter); subtile offset = (h*2+s)*64*K precomputed once. Fragment reads
// are base+immediate from per-hf hoisted pointers. This removes the per-phase
// 64-bit muls that made VALUBusy ~30% (R5 post-mortem).
// vmcnt(4) steady-state invariant (traced R2): after each mp3 wait, the 4 newest
// outstanding loads are exactly the next B-tile; everything the next half-iter
// reads has landed.
// EPI: 0 +bias[col]->bf16 | 1 *scale->bf16 | 3 +bias[col]->f32 | 4 +bias[row]->bf16
//      5 exp2(acc*scale)->bf16 + row-partial sums to aux | 6 acc*bias[row]+resid->bf16
template <int EPI>
__global__ __launch_bounds__(512, 2) void gemm256(
    const unsigned short* __restrict__ A, const unsigned short* __restrict__ B,
    void* __restrict__ C, const float* __restrict__ bias,
    const unsigned short* __restrict__ resid, float* __restrict__ aux,
    int N, int K, long sA, long sB, long sC, long sR, float scale) {
  __shared__ char lds[131072];
  const int t = threadIdx.x;
  const int lane = t & 63, wid = t >> 6;

  const int gx = gridDim.x, gy = gridDim.y;
  int bid = blockIdx.x + gx * (blockIdx.y + gy * blockIdx.z);
  const int nwg = gx * gy * (int)gridDim.z;
  const int chunk = nwg >> 3;
  int lid = (bid & 7) * chunk + (bid >> 3);
  const int bn = lid % gx; lid /= gx;
  const int bm = lid % gy;
  const int bz = lid / gy;

  const unsigned short* Ab = A + (long)bz * sA + (long)bm * 256 * K;
  const unsigned short* Bb = B + (long)bz * sB + (long)bn * 256 * K;

  // staging: linear LDS dest, inverse-swizzled global source (rule #21)
  const int colswz = ((lane & 3) * 8) ^ ((lane >> 5) * 16);
  const int r0s = (wid >> 1) * 16 + (lane >> 2);
  const int scol = (wid & 1) * 32 + colswz;

  // running per-wave source pointers (advance +128 elems = 2 K-tiles per iter)
  const unsigned short* aPtr = Ab + (long)r0s * K + scol;
  const unsigned short* bPtr = Bb + (long)r0s * K + scol;
  const long off_s = (long)64 * K;            // one 64-row subtile step
  const int  widB  = wid * 1024;

  auto issue = [&](const unsigned short* p, int h, int bufbyte) {
#pragma unroll
    for (int s = 0; s < 2; ++s) {
      const unsigned short* src = p + (h * 2 + s) * off_s;
      char* dst = lds + bufbyte + h * 16384 + s * 8192 + widB;
      __builtin_amdgcn_global_load_lds(
          (const __attribute__((address_space(1))) void*)src,
          (__attribute__((address_space(3))) void*)dst, 16, 0, 0);
    }
  };

  // fragment-read pieces
  const int wm = wid >> 2, wn = wid & 3;
  const int fr = lane & 15, kg = lane >> 4;
  const int lanePart = (fr * 64 + kg * 16) ^ ((fr >> 3) << 5);

  f32x4 acc[8][4] = {};
  const int NT = K >> 6;
  const int NITER = NT >> 1;

  // prologue: A0 -> abuf0, B0 -> bbuf0, B1 -> bbuf1; wait A0+B0, B1 in flight
  issue(aPtr, 0, 0);          issue(aPtr, 1, 0);
  issue(bPtr, 0, 65536);      issue(bPtr, 1, 65536);
  issue(bPtr + 64, 0, 98304); issue(bPtr + 64, 1, 98304);
  asm volatile("s_waitcnt vmcnt(4)" ::: "memory");
  __builtin_amdgcn_s_barrier();

  for (int it = 0; it < NITER; ++it) {
    const bool last = (it == NITER - 1);
#pragma unroll
    for (int hf = 0; hf < 2; ++hf) {
      const char* aB = lds + hf * 32768 + wm * 16384 + lanePart;
      const char* bB = lds + 65536 + hf * 32768 + wn * 8192 + lanePart;
      bf16x8 bv[4][2];
      bf16x8 av[2][2];
#pragma unroll
      for (int mp = 0; mp < 4; ++mp) {
        // --- ds_reads for THIS phase (base + immediate) ---
        if (mp == 0) {
#pragma unroll
          for (int n = 0; n < 4; ++n)
#pragma unroll
            for (int kk = 0; kk < 2; ++kk)
              bv[n][kk] = *(const bf16x8*)(bB + n * 2048 + kk * 1024);
        }
#pragma unroll
        for (int ml = 0; ml < 2; ++ml)
#pragma unroll
          for (int kk = 0; kk < 2; ++kk)
            av[ml][kk] = *(const bf16x8*)(aB + (mp * 2 + ml) * 2048 + kk * 1024);
        // --- staging issues (schedule identical to the twice-refcheck'd version) ---
        if (hf == 0) {
          if (mp == 0) issue(aPtr + 64, 0, 32768);
          else if (mp == 1) { issue(aPtr + 64, 1, 32768); if (!last) issue(bPtr + 128, 0, 65536); }
          else if (mp == 2) { if (!last) issue(bPtr + 128, 1, 65536); }
          else {
            if (last) asm volatile("s_waitcnt vmcnt(0)" ::: "memory");
            else      asm volatile("s_waitcnt vmcnt(4)" ::: "memory");
          }
        } else if (!last) {
          if (mp == 0) issue(aPtr + 128, 0, 0);
          else if (mp == 1) { issue(aPtr + 128, 1, 0); issue(bPtr + 192, 0, 98304); }
          else if (mp == 2) issue(bPtr + 192, 1, 98304);
          else asm volatile("s_waitcnt vmcnt(4)" ::: "memory");
        }
        __builtin_amdgcn_s_barrier();
        asm volatile("s_waitcnt lgkmcnt(0)" ::: "memory");
        __builtin_amdgcn_sched_barrier(0);
        __builtin_amdgcn_s_setprio(1);
#pragma unroll
        for (int kk = 0; kk < 2; ++kk)
#pragma unroll
          for (int ml = 0; ml < 2; ++ml)
#pragma unroll
            for (int n = 0; n < 4; ++n)
              acc[mp * 2 + ml][n] = __builtin_amdgcn_mfma_f32_16x16x32_bf16(
                  av[ml][kk], bv[n][kk], acc[mp * 2 + ml][n], 0, 0, 0);
        __builtin_amdgcn_s_setprio(0);
        __builtin_amdgcn_s_barrier();
      }
    }
    aPtr += 128;
    bPtr += 128;
  }

  // C/D layout: col = lane&15, row = (lane>>4)*4 + reg  [m89/m91]
  const int row0 = bm * 256 + wm * 128 + kg * 4;
  const int col0 = bn * 256 + wn * 64 + fr;
  const long cb = (long)bz * sC;

  if constexpr (EPI == 5) {
    // e = exp2(acc*scale) (no max-sub; |scores| << 1), store bf16, row-sums -> aux
    float* lf = (float*)lds;   // 4 KiB scratch; all loop ds_reads drained
#pragma unroll
    for (int m = 0; m < 8; ++m) {
#pragma unroll
      for (int r = 0; r < 4; ++r) {
        const int row = row0 + m * 16 + r;
        float sv = 0.f;
#pragma unroll
        for (int n = 0; n < 4; ++n) {
          float e = exp2f(acc[m][n][r] * scale);
          unsigned short eb = f2bf(e);
          ((unsigned short*)C)[cb + (long)row * N + col0 + n * 16] = eb;
          sv += bf2f(eb);
        }
#pragma unroll
        for (int o = 1; o < 16; o <<= 1) sv += __shfl_xor(sv, o);
        if ((lane & 15) == 0)
          lf[wn * 256 + wm * 128 + m * 16 + kg * 4 + r] = sv;
      }
    }
    __syncthreads();
    if (t < 256) {
      float s4 = lf[t] + lf[256 + t] + lf[512 + t] + lf[768 + t];
      aux[((long)bz * 2048 + bm * 256 + t) * 8 + bn] = s4;
    }
    return;
  }

#pragma unroll
  for (int m = 0; m < 8; ++m)
#pragma unroll
    for (int n = 0; n < 4; ++n) {
      const int col = col0 + n * 16;
#pragma unroll
      for (int r = 0; r < 4; ++r) {
        const int row = row0 + m * 16 + r;
        float v = acc[m][n][r];
        if constexpr (EPI == 0) {
          v += bias[col];
          ((unsigned short*)C)[cb + (long)row * N + col] = f2bf(v);
        } else if constexpr (EPI == 1) {
          v *= scale;
          ((unsigned short*)C)[cb + (long)row * N + col] = f2bf(v);
        } else if constexpr (EPI == 3) {
          v += bias[col];
          ((float*)C)[cb + (long)row * N + col] = v;
        } else if constexpr (EPI == 4) {
          v += bias[row];
          ((unsigned short*)C)[cb + (long)row * N + col] = f2bf(v);
        } else {  // EPI == 6: PV normalize by invL[row] + residual q
          v = v * bias[(long)bz * 2048 + row] + bf2f(resid[(long)bz * sR + (long)row * N + col]);
          ((unsigned short*)C)[cb + (long)row * N + col] = f2bf(v);
        }
      }
    }
}

// ---------------- orchestration ----------------
extern "C" void kernel_launch(void* const* d_in, const int* in_sizes, int n_in,
                              void* d_out, int out_size, void* d_ws, size_t ws_size,
                              hipStream_t stream) {
  (void)in_sizes; (void)n_in; (void)out_size; (void)ws_size;
  const float* hist = (const float*)d_in[0];
  const float* comb = (const float*)d_in[1];
  const float* hW = (const float*)d_in[2];  const float* hb = (const float*)d_in[3];
  const float* cW = (const float*)d_in[4];  const float* cb = (const float*)d_in[5];
  const float* qW = (const float*)d_in[6];  const float* qb = (const float*)d_in[7];
  const float* kW = (const float*)d_in[8];
  const float* vW = (const float*)d_in[10]; const float* vb = (const float*)d_in[11];
  const float* oW = (const float*)d_in[12]; const float* ob = (const float*)d_in[13];

  constexpr int  Bn = 8, L = 2048, F = 1024;
  constexpr long NE = (long)Bn * L * F;
  constexpr long WE = (long)F * F;

  char* ws = (char*)d_ws;
  size_t off = 0;
  unsigned short* oWb = (unsigned short*)(ws + off); off += WE * 2;
  unsigned short* Wq  = (unsigned short*)(ws + off); off += WE * 2;
  unsigned short* Wkv = (unsigned short*)(ws + off); off += 2 * WE * 2;
  unsigned short* Wk  = Wkv;
  unsigned short* Wv  = Wkv + WE;
  float* bq = (float*)(ws + off); off += F * 4;
  float* bv = (float*)(ws + off); off += F * 4;
  float* Lpart = (float*)(ws + off); off += (size_t)Bn * L * 8 * 4;
  float* invL  = (float*)(ws + off); off += (size_t)Bn * L * 4;
  unsigned short* A0 = (unsigned short*)(ws + off); off += NE * 2;
  unsigned short* A1 = (unsigned short*)(ws + off); off += NE * 2;
  unsigned short* A2 = (unsigned short*)(ws + off); off += NE * 2;
  unsigned short* A3 = (unsigned short*)(ws + off); off += NE * 2;
  unsigned short* S  = (unsigned short*)(ws + off); off += (size_t)Bn * L * L * 2;
  // temp weights overlaid on S (dead before scores GEMM writes S)
  unsigned short* hWt = S;
  unsigned short* cWt = S + WE;
  unsigned short* qWb = S + 2 * WE;
  unsigned short* kvWb = S + 3 * WE;

  transpose_cast<<<dim3(16, 16, 1), 256, 0, stream>>>(hW, hWt, F, F);
  transpose_cast<<<dim3(16, 16, 1), 256, 0, stream>>>(cW, cWt, F, F);
  cvt_f32_to_bf16<<<512, 256, 0, stream>>>(qW, qWb, WE / 8);
  cvt_f32_to_bf16<<<512, 256, 0, stream>>>(kW, kvWb, WE / 8);
  cvt_f32_to_bf16<<<512, 256, 0, stream>>>(vW, kvWb + WE, WE / 8);
  cvt_f32_to_bf16<<<512, 256, 0, stream>>>(oW, oWb, WE / 8);
  cvt_f32_to_bf16<<<2048, 256, 0, stream>>>(hist, A0, NE / 8);
  cvt_f32_to_bf16<<<2048, 256, 0, stream>>>(comb, A1, NE / 8);

  // combined biases: bq = qW·hb + qb ; bv = vW·cb + vb   (bk cancels in softmax)
  bias_matvec<<<F, 256, 0, stream>>>(qW, hb, qb, bq, F);
  bias_matvec<<<F, 256, 0, stream>>>(vW, cb, vb, bv, F);

  // combined weights: Wq = qW·hW ; [Wk;Wv] = [kW;vW]·cW
  gemm_bt<1><<<dim3(8, 8, 1), 256, 0, stream>>>(qWb, hWt, Wq, nullptr,
      1024, 1024, 1024, 1.0f);
  gemm_bt<1><<<dim3(8, 16, 1), 256, 0, stream>>>(kvWb, cWt, Wkv, nullptr,
      2048, 1024, 1024, 1.0f);

  const float S2 = 0.03125f * 1.44269504089f;  // (1/sqrt(F)) * log2(e), for exp2

  // q = hist·Wq^T + bq          -> A2
  gemm256<0><<<dim3(4, 64, 1), 512, 0, stream>>>(A0, Wq, A2, bq, nullptr, nullptr,
      1024, 1024, 0, 0, 0, 0, 0.f);
  // k = comb·Wk^T (no bias)     -> A0
  gemm256<1><<<dim3(4, 64, 1), 512, 0, stream>>>(A1, Wk, A0, nullptr, nullptr, nullptr,
      1024, 1024, 0, 0, 0, 0, 1.0f);
  // vt[b][f][l] = Wv·comb_b^T + bv[row]  -> A3
  gemm256<4><<<dim3(8, 4, Bn), 512, 0, stream>>>(Wv, A1, A3, bv, nullptr, nullptr,
      2048, 1024, 0, (long)L * F, (long)F * L, 0, 0.f);
  // E = exp2(q·k^T · S2)        -> S, row-sum partials -> Lpart
  gemm256<5><<<dim3(8, 8, Bn), 512, 0, stream>>>(A2, A0, S, nullptr, nullptr, Lpart,
      2048, 1024, (long)L * F, (long)L * F, (long)L * L, 0, S2);
  // invL = 1/rowsum
  merge_invl<<<64, 256, 0, stream>>>(Lpart, invL, (long)Bn * L);
  // ao = (E·vt^T)·invL + q      -> A1
  gemm256<6><<<dim3(4, 8, Bn), 512, 0, stream>>>(S, A3, A1, invL, A2, nullptr,
      1024, 2048, (long)L * L, (long)F * L, (long)L * F, (long)L * F, 0.f);
  // out = ao·oW^T + ob          -> d_out (f32)
  gemm256<3><<<dim3(4, 64, 1), 512, 0, stream>>>(A1, oWb, (float*)d_out, ob, nullptr, nullptr,
      1024, 1024, 0, 0, 0, 0, 0.f);
}